// Round 6
// baseline (749.562 us; speedup 1.0000x reference)
//
#include <hip/hip_runtime.h>
#include <hip/hip_bf16.h>

typedef __bf16 bf16_t;
typedef bf16_t bf16x8 __attribute__((ext_vector_type(8)));
typedef bf16_t bf16x4 __attribute__((ext_vector_type(4)));
typedef float f32x4 __attribute__((ext_vector_type(4)));

#define DIN 1024
#define DH 1024
#define DMOE 4096
#define NEXP 8
#define NTOK 4096

__device__ __forceinline__ void gload_lds16(const bf16_t* g, bf16_t* l) {
  __builtin_amdgcn_global_load_lds(
      (const __attribute__((address_space(1))) void*)g,
      (__attribute__((address_space(3))) void*)l, 16, 0, 0);
}

// ---------------- small utility kernels ----------------

__global__ void k_zero8(int* p) {
  if (threadIdx.x < 8) p[threadIdx.x] = 0;
}

// src [b][R][C] f32 -> dst [b][C][R] bf16
__global__ void k_transpose_cvt(const float* __restrict__ src, bf16_t* __restrict__ dst,
                                int R, int C) {
  __shared__ float tile[32][33];
  const size_t mofs = (size_t)blockIdx.z * R * C;
  const float* s = src + mofs;
  bf16_t* d = dst + mofs;
  const int c0 = blockIdx.x * 32, r0 = blockIdx.y * 32;
  const int tx = threadIdx.x, ty = threadIdx.y;
#pragma unroll
  for (int i = 0; i < 32; i += 8)
    tile[ty + i][tx] = s[(size_t)(r0 + ty + i) * C + (c0 + tx)];
  __syncthreads();
#pragma unroll
  for (int i = 0; i < 32; i += 8)
    d[(size_t)(c0 + ty + i) * R + (r0 + tx)] = (bf16_t)tile[tx][ty + i];
}

__global__ void k_cvt_bf16(const float* __restrict__ src, bf16_t* __restrict__ dst, int n4) {
  const int i = blockIdx.x * blockDim.x + threadIdx.x;
  if (i < n4) {
    const float4 v = *(const float4*)(src + (size_t)i * 4);
    bf16x4 o;
    o.x = (bf16_t)v.x; o.y = (bf16_t)v.y; o.z = (bf16_t)v.z; o.w = (bf16_t)v.w;
    *(bf16x4*)(dst + (size_t)i * 4) = o;
  }
}

// G[d][e] = sum_k W_in[d][k] * W_gate[k][e]  (fp64); row d==DH computes c[e] from b_in
__global__ void k_gate_prep(const float* __restrict__ Win, const float* __restrict__ Wgate,
                            const float* __restrict__ b_in, const float* __restrict__ b_gate,
                            double* __restrict__ G, double* __restrict__ cvec) {
  const int lane = threadIdx.x & 63;
  const int wave = (blockIdx.x * blockDim.x + threadIdx.x) >> 6;
  const int nw = (gridDim.x * blockDim.x) >> 6;
  for (int d = wave; d <= DIN; d += nw) {
    const float* row = (d < DIN) ? (Win + (size_t)d * DH) : b_in;
    double acc[8] = {0, 0, 0, 0, 0, 0, 0, 0};
    for (int k = lane; k < DH; k += 64) {
      const double xv = (double)row[k];
      const float* g = Wgate + (size_t)k * NEXP;
#pragma unroll
      for (int ee = 0; ee < 8; ++ee) acc[ee] += xv * (double)g[ee];
    }
#pragma unroll
    for (int ee = 0; ee < 8; ++ee) {
      double a = acc[ee];
      for (int o = 32; o > 0; o >>= 1) a += __shfl_down(a, o);
      acc[ee] = a;
    }
    if (lane == 0) {
      if (d < DIN) {
#pragma unroll
        for (int ee = 0; ee < 8; ++ee) G[(size_t)d * 8 + ee] = acc[ee];
      } else {
#pragma unroll
        for (int ee = 0; ee < 8; ++ee) cvec[ee] = acc[ee] + (double)b_gate[ee];
      }
    }
  }
}

// per token: fp64 logits via fused G, softmax, top-2, scatter into expert lists
__global__ void k_gating(const float* __restrict__ x, const double* __restrict__ G,
                         const double* __restrict__ cvec, int* __restrict__ cnt,
                         int* __restrict__ list, float* __restrict__ wlist) {
  const int lane = threadIdx.x & 63;
  const int t = blockIdx.x * (blockDim.x >> 6) + (threadIdx.x >> 6);
  if (t >= NTOK) return;
  const float* xr = x + (size_t)t * DIN;
  double acc[8] = {0, 0, 0, 0, 0, 0, 0, 0};
  for (int d = lane; d < DIN; d += 64) {
    const double xv = (double)xr[d];
    const double* g = G + (size_t)d * 8;
#pragma unroll
    for (int ee = 0; ee < 8; ++ee) acc[ee] += xv * g[ee];
  }
#pragma unroll
  for (int ee = 0; ee < 8; ++ee) {
    double a = acc[ee];
    for (int o = 32; o > 0; o >>= 1) a += __shfl_down(a, o);
    acc[ee] = a;
  }
  if (lane == 0) {
    double l[8];
#pragma unroll
    for (int ee = 0; ee < 8; ++ee) l[ee] = acc[ee] + cvec[ee];
    double m = l[0];
#pragma unroll
    for (int ee = 1; ee < 8; ++ee) m = fmax(m, l[ee]);
    double p[8];
#pragma unroll
    for (int ee = 0; ee < 8; ++ee) p[ee] = exp(l[ee] - m);
    int i1 = 0;
#pragma unroll
    for (int ee = 1; ee < 8; ++ee)
      if (p[ee] > p[i1]) i1 = ee;
    int i2 = (i1 == 0) ? 1 : 0;
#pragma unroll
    for (int ee = 0; ee < 8; ++ee)
      if (ee != i1 && p[ee] > p[i2]) i2 = ee;
    const double s2 = p[i1] + p[i2];
    const float w1 = (float)(p[i1] / s2);
    const float w2 = (float)(p[i2] / s2);
    int lp = atomicAdd(&cnt[i1], 1);
    list[i1 * NTOK + lp] = t * 2;
    wlist[i1 * NTOK + lp] = w1;
    lp = atomicAdd(&cnt[i2], 1);
    list[i2 * NTOK + lp] = t * 2 + 1;
    wlist[i2 * NTOK + lp] = w2;
  }
}

__global__ void k_scan(const int* __restrict__ cnt, int* __restrict__ offs) {
  if (threadIdx.x == 0) {
    int s = 0;
    for (int e = 0; e < NEXP; ++e) { offs[e] = s; s += cnt[e]; }
    offs[NEXP] = s;
  }
}

// moe_bf16[t] = bf16(eout[t][0] + eout[t][1])   (route weights already applied)
__global__ void k_combine(const float* __restrict__ eout, bf16_t* __restrict__ moebf) {
  const int i = blockIdx.x * blockDim.x + threadIdx.x;
  const int t = i >> 8;
  const int q = (i & 255) * 4;
  const float4 a = *(const float4*)(eout + ((size_t)t * 2) * DH + q);
  const float4 b = *(const float4*)(eout + ((size_t)t * 2 + 1) * DH + q);
  bf16x4 o;
  o.x = (bf16_t)(a.x + b.x); o.y = (bf16_t)(a.y + b.y);
  o.z = (bf16_t)(a.z + b.z); o.w = (bf16_t)(a.w + b.w);
  *(bf16x4*)(moebf + (size_t)t * DH + q) = o;
}

// ---------------- 128x128 BK=32 plain GEMM (round-2 proven), 4 waves ----------------
// MODE 0: plain, bf16 out. MODE 3: plain, fp32 out.
template <int MODE>
__global__ __launch_bounds__(256, 3) void k_gemm128(
    const bf16_t* __restrict__ A, const bf16_t* __restrict__ B,
    const float* __restrict__ bias, void* __restrict__ Cbase,
    int M, int N, int K) {
  const int mblk = blockIdx.y, nblk = blockIdx.x;

  __shared__ bf16_t As[3][128 * 32];
  __shared__ bf16_t Bs[3][128 * 32];

  const int tid = threadIdx.x;
  const int lane = tid & 63;
  const int wid = tid >> 6;
  const int wr = wid >> 1, wc = wid & 1;

  const int srow0 = wid * 32 + (lane >> 2);
  const int srow1 = srow0 + 16;
  const int skcol = (lane & 3) * 8;

  const bf16_t* aptr0 = A + (size_t)(mblk * 128 + srow0) * K + skcol;
  const bf16_t* aptr1 = A + (size_t)(mblk * 128 + srow1) * K + skcol;
  const bf16_t* bptr0 = B + (size_t)(nblk * 128 + srow0) * K + skcol;
  const bf16_t* bptr1 = B + (size_t)(nblk * 128 + srow1) * K + skcol;

  const int ldsOfsA0 = (wid * 32) * 32;
  const int ldsOfsA1 = (wid * 32 + 16) * 32;

  f32x4 acc[4][4] = {};
  const int nkt = K >> 5;

  auto stage = [&](int buf, int kt) {
    const size_t ko = (size_t)kt * 32;
    gload_lds16(aptr0 + ko, &As[buf][ldsOfsA0]);
    gload_lds16(aptr1 + ko, &As[buf][ldsOfsA1]);
    gload_lds16(bptr0 + ko, &Bs[buf][ldsOfsA0]);
    gload_lds16(bptr1 + ko, &Bs[buf][ldsOfsA1]);
  };

  stage(0, 0);
  if (nkt > 1) stage(1, 1);

  int cur = 0;
  for (int kt = 0; kt < nkt; ++kt) {
    int nxt = cur + 2;
    if (nxt >= 3) nxt -= 3;
    if (kt + 2 < nkt) {
      stage(nxt, kt + 2);
      asm volatile("s_waitcnt vmcnt(8)" ::: "memory");
    } else if (kt + 1 < nkt) {
      asm volatile("s_waitcnt vmcnt(4)" ::: "memory");
    } else {
      asm volatile("s_waitcnt vmcnt(0)" ::: "memory");
    }
    __builtin_amdgcn_s_barrier();

    const int fr = lane & 15;
    const int kq = (lane >> 4) * 8;
    bf16x8 af[4], bfr[4];
#pragma unroll
    for (int m = 0; m < 4; ++m)
      af[m] = *(const bf16x8*)&As[cur][(wr * 64 + m * 16 + fr) * 32 + kq];
#pragma unroll
    for (int n = 0; n < 4; ++n)
      bfr[n] = *(const bf16x8*)&Bs[cur][(wc * 64 + n * 16 + fr) * 32 + kq];
#pragma unroll
    for (int m = 0; m < 4; ++m)
#pragma unroll
      for (int n = 0; n < 4; ++n)
        acc[m][n] = __builtin_amdgcn_mfma_f32_16x16x32_bf16(af[m], bfr[n], acc[m][n], 0, 0, 0);

    __builtin_amdgcn_s_barrier();
    cur += 1;
    if (cur >= 3) cur -= 3;
  }

  const int colBase = nblk * 128 + wc * 64 + (lane & 15);
  const int rowBase = mblk * 128 + wr * 64 + ((lane >> 4) << 2);
#pragma unroll
  for (int n = 0; n < 4; ++n) {
    const int c = colBase + n * 16;
    const float bv = bias[c];
#pragma unroll
    for (int m = 0; m < 4; ++m) {
#pragma unroll
      for (int j = 0; j < 4; ++j) {
        const int r = rowBase + m * 16 + j;
        const float v = acc[m][n][j] + bv;
        if constexpr (MODE == 0) {
          ((bf16_t*)Cbase)[(size_t)r * N + c] = (bf16_t)v;
        } else {
          ((float*)Cbase)[(size_t)r * N + c] = v;
        }
      }
    }
  }
}

// ---------------- 256x256 BK=64 expert GEMM, 8 waves, true 8-phase (m201) ----------
// T1 remap + T2 both-sides swizzle + T3/T4 slab-staggered counted vmcnt + T5 setprio.
// Per 2-K-tile iteration: 8 phases, each {4-8 ds_read | 0-4 gload_lds | bar |
// lgkmcnt(0)+sched_barrier | 16 MFMA | bar}. vmcnt(4) checkpoints at P4/P8 only.
// MODE 1: A rows gathered via list (token=entry>>1), relu, bf16 out at rowOff+r
// MODE 2: A = mid + rowOff, fp32 out scattered to eout[entry][*] scaled by wlist
template <int MODE>
__global__ __launch_bounds__(512, 2) void k_gemm256(
    const bf16_t* __restrict__ Abase, const bf16_t* __restrict__ Bbase,
    const float* __restrict__ biasBase, void* __restrict__ Cbase,
    int N, int K,
    const int* __restrict__ cnt, const int* __restrict__ offs,
    const int* __restrict__ listBase, const float* __restrict__ wlistBase) {
  const int e = blockIdx.z;
  const int mtiles = gridDim.y;
  const int hw = blockIdx.y * gridDim.x + blockIdx.x;
  const int cpx = (gridDim.x * gridDim.y) >> 3;
  const int lid = (hw & 7) * cpx + (hw >> 3);
  const int mblk = lid % mtiles;
  const int nblk = lid / mtiles;

  const int Mloc = cnt[e];
  if (mblk * 256 >= Mloc) return;  // uniform early exit, before any barrier
  const bf16_t* B = Bbase + (size_t)e * N * K;
  const float* bias = biasBase + (size_t)e * N;
  const int* myList = listBase + e * NTOK;
  const float* myW = wlistBase + e * NTOK;
  const int rowOff = offs[e];
  const bf16_t* A = (MODE == 2) ? (Abase + (size_t)rowOff * K) : Abase;

  __shared__ bf16_t As[4 * 128 * 64];  // slab (buf*2+h): [128][64]
  __shared__ bf16_t Bs[4 * 128 * 64];

  const int tid = threadIdx.x;
  const int lane = tid & 63;
  const int wid = tid >> 6;  // 0..7
  const int wr = wid >> 2;   // A half owned for reads
  const int wcn = wid & 3;   // N quarter

  // staging source (pre-swizzled col group; both-sides rule #21)
  const int sub_r = lane >> 3;
  const int colg = ((lane & 7) ^ sub_r) * 8;
  uint32_t aoff[2][2], boff[2][2];
#pragma unroll
  for (int h = 0; h < 2; ++h) {
#pragma unroll
    for (int l = 0; l < 2; ++l) {
      const int c = wid * 2 + l;
      int ar = mblk * 256 + h * 128 + c * 8 + sub_r;
      const int br = nblk * 256 + h * 128 + c * 8 + sub_r;
      if (ar > Mloc - 1) ar = Mloc - 1;
      uint32_t arow = (uint32_t)ar;
      if constexpr (MODE == 1) arow = (uint32_t)(myList[ar] >> 1);
      aoff[h][l] = arow * (uint32_t)K + colg;
      boff[h][l] = (uint32_t)br * (uint32_t)K + colg;
    }
  }

  auto stA = [&](int buf, int h, int kt) {
    const uint32_t ko = (uint32_t)kt * 64;
    gload_lds16(A + aoff[h][0] + ko, &As[(buf * 2 + h) * 8192 + (wid * 2 + 0) * 512]);
    gload_lds16(A + aoff[h][1] + ko, &As[(buf * 2 + h) * 8192 + (wid * 2 + 1) * 512]);
  };
  auto stB = [&](int buf, int h, int kt) {
    const uint32_t ko = (uint32_t)kt * 64;
    gload_lds16(B + boff[h][0] + ko, &Bs[(buf * 2 + h) * 8192 + (wid * 2 + 0) * 512]);
    gload_lds16(B + boff[h][1] + ko, &Bs[(buf * 2 + h) * 8192 + (wid * 2 + 1) * 512]);
  };

  const int fr = lane & 15;
  const int s0 = (((lane >> 4) ^ (fr & 7)) << 3);  // kh0 slot; kh1 = s0^32
  const int brow0 = (wcn & 1) * 64;
  const bf16_t* A0 = &As[(0 + wr) * 8192];         // buf0 A slab (this wave)
  const bf16_t* A1 = &As[(2 + wr) * 8192];         // buf1 A slab
  const bf16_t* B0 = &Bs[(0 + (wcn >> 1)) * 8192];
  const bf16_t* B1 = &Bs[(2 + (wcn >> 1)) * 8192];

  f32x4 acc[8][4] = {};
  const int nkt = K >> 6;
  const int iters = nkt >> 1;

  bf16x8 a[4], a2[4], b[4];

  auto rdA = [&](bf16x8* dst, const bf16_t* base, int mo, int s) {
#pragma unroll
    for (int m = 0; m < 4; ++m)
      dst[m] = *(const bf16x8*)&base[((m + mo) * 16 + fr) * 64 + s];
  };
  auto rdB = [&](bf16x8* dst, const bf16_t* base, int s) {
#pragma unroll
    for (int n = 0; n < 4; ++n)
      dst[n] = *(const bf16x8*)&base[(brow0 + n * 16 + fr) * 64 + s];
  };
  auto mfma16 = [&](bf16x8* av, bf16x8* bv, int mo) {
#pragma unroll
    for (int m = 0; m < 4; ++m)
#pragma unroll
      for (int n = 0; n < 4; ++n)
        acc[m + mo][n] =
            __builtin_amdgcn_mfma_f32_16x16x32_bf16(av[m], bv[n], acc[m + mo][n], 0, 0, 0);
  };

#define PHASE_MID()                                        \
  __builtin_amdgcn_s_barrier();                            \
  asm volatile("s_waitcnt lgkmcnt(0)" ::: "memory");       \
  __builtin_amdgcn_sched_barrier(0);                       \
  __builtin_amdgcn_s_setprio(1)
#define PHASE_END()                                        \
  __builtin_amdgcn_s_setprio(0);                           \
  __builtin_amdgcn_s_barrier()

  // prologue: buf0 <- tile0 (all 4 slabs), buf1 <- tile1 first halves (Ah0,Bh0)
  stA(0, 0, 0); stB(0, 0, 0); stA(0, 1, 0); stB(0, 1, 0);
  stA(1, 0, 1); stB(1, 0, 1);
  asm volatile("s_waitcnt vmcnt(4)" ::: "memory");
  __builtin_amdgcn_s_barrier();

  for (int it = 0; it < iters; ++it) {
    const int t0 = 2 * it, t1 = 2 * it + 1;
    const bool pf2 = (t0 + 2 < nkt);
    const bool pf3 = (t1 + 2 < nkt);
    // P1: buf0 kh0 (A m0-3, B); finish staging buf1 <- tile t1 (Ah1,Bh1)
    rdA(a, A0, 0, s0); rdB(b, B0, s0);
    stA(1, 1, t1); stB(1, 1, t1);
    PHASE_MID(); mfma16(a, b, 0); PHASE_END();
    // P2: buf0 kh0 A m4-7
    rdA(a2, A0, 4, s0);
    PHASE_MID(); mfma16(a2, b, 4); PHASE_END();
    // P3: buf0 kh1 (A m0-3, B)
    rdA(a, A0, 0, s0 ^ 32); rdB(b, B0, s0 ^ 32);
    PHASE_MID(); mfma16(a, b, 0); PHASE_END();
    // P4: buf0 kh1 A m4-7; stage buf0.{Ah0,Bh0} <- tile t0+2; checkpoint buf1 staged
    rdA(a2, A0, 4, s0 ^ 32);
    if (pf2) { stA(0, 0, t0 + 2); stB(0, 0, t0 + 2); }
    PHASE_MID(); mfma16(a2, b, 4);
    __builtin_amdgcn_s_setprio(0);
    if (pf2) { asm volatile("s_waitcnt vmcnt(4)" ::: "memory"); }
    else     { asm volatile("s_waitcnt vmcnt(0)" ::: "memory"); }
    __builtin_amdgcn_s_barrier();
    // P5: buf1 kh0 (A m0-3, B); stage buf0.{Ah1,Bh1}
    rdA(a, A1, 0, s0); rdB(b, B1, s0);
    if (pf2) { stA(0, 1, t0 + 2); stB(0, 1, t0 + 2); }
    PHASE_MID(); mfma16(a, b, 0); PHASE_END();
    // P6: buf1 kh0 A m4-7
    rdA(a2, A1, 4, s0);
    PHASE_MID(); mfma16(a2, b, 4); PHASE_END();
    // P7: buf1 kh1 (A m0-3, B)
    rdA(a, A1, 0, s0 ^ 32); rdB(b, B1, s0 ^ 32);
    PHASE_MID(); mfma16(a, b, 0); PHASE_END();
    // P8: buf1 kh1 A m4-7; stage buf1.{Ah0,Bh0} <- tile t1+2; checkpoint buf0 staged
    rdA(a2, A1, 4, s0 ^ 32);
    if (pf3) { stA(1, 0, t1 + 2); stB(1, 0, t1 + 2); }
    PHASE_MID(); mfma16(a2, b, 4);
    __builtin_amdgcn_s_setprio(0);
    if (pf3) { asm volatile("s_waitcnt vmcnt(4)" ::: "memory"); }
    __builtin_amdgcn_s_barrier();
  }
#undef PHASE_MID
#undef PHASE_END

  // epilogue
  const int colBase = nblk * 256 + wcn * 64 + (lane & 15);
  const int rowBase = mblk * 256 + wr * 128 + ((lane >> 4) << 2);
#pragma unroll
  for (int n = 0; n < 4; ++n) {
    const int c = colBase + n * 16;
    const float bv = bias[c];
#pragma unroll
    for (int m = 0; m < 8; ++m) {
#pragma unroll
      for (int j = 0; j < 4; ++j) {
        const int r = rowBase + m * 16 + j;
        float v = acc[m][n][j] + bv;
        if (r < Mloc) {
          if constexpr (MODE == 1) {
            v = fmaxf(v, 0.0f);
            ((bf16_t*)Cbase)[(size_t)(rowOff + r) * N + c] = (bf16_t)v;
          } else {
            const int entry = myList[r];
            const float w = myW[r];
            ((float*)Cbase)[(size_t)entry * DH + c] = v * w;
          }
        }
      }
    }
  }
}

// ---------------- launch ----------------

extern "C" void kernel_launch(void* const* d_in, const int* in_sizes, int n_in,
                              void* d_out, int out_size, void* d_ws, size_t ws_size,
                              hipStream_t stream) {
  const float* x      = (const float*)d_in[0];
  const float* W_in   = (const float*)d_in[1];
  const float* b_in   = (const float*)d_in[2];
  const float* W_gate = (const float*)d_in[3];
  const float* b_gate = (const float*)d_in[4];
  const float* W1     = (const float*)d_in[5];
  const float* b1     = (const float*)d_in[6];
  const float* W2     = (const float*)d_in[7];
  const float* b2     = (const float*)d_in[8];
  const float* W_out  = (const float*)d_in[9];
  const float* b_out  = (const float*)d_in[10];

  char* ws = (char*)d_ws;
  size_t off = 0;
  auto alloc = [&](size_t bytes) -> void* {
    void* p = ws + off;
    off += (bytes + 255) & ~(size_t)255;
    return p;
  };

  bf16_t* WtIn  = (bf16_t*)alloc((size_t)DH * DIN * 2);          // [DH][DIN]
  bf16_t* Wt1   = (bf16_t*)alloc((size_t)NEXP * DMOE * DH * 2);  // [E][DMOE][DH]
  bf16_t* Wt2   = (bf16_t*)alloc((size_t)NEXP * DH * DMOE * 2);  // [E][DH][DMOE]
  bf16_t* WtOut = (bf16_t*)alloc((size_t)DH * DH * 2);           // [DOUT][DH]
  bf16_t* xbf   = (bf16_t*)alloc((size_t)NTOK * DIN * 2);
  bf16_t* hbf   = (bf16_t*)alloc((size_t)NTOK * DH * 2);
  bf16_t* mid   = (bf16_t*)alloc((size_t)2 * NTOK * DMOE * 2);   // [2N][DMOE]
  float*  eout  = (float*)alloc((size_t)2 * NTOK * DH * 4);      // [2N][DH] (t*2+slot)
  bf16_t* moebf = (bf16_t*)alloc((size_t)NTOK * DH * 2);
  double* G     = (double*)alloc((size_t)DIN * 8 * 8);
  double* cvec  = (double*)alloc(8 * 8);
  int*    cnt   = (int*)alloc(NEXP * 4);
  int*    offs  = (int*)alloc((NEXP + 1) * 4);
  int*    list  = (int*)alloc((size_t)NEXP * NTOK * 4);
  float*  wlist = (float*)alloc((size_t)NEXP * NTOK * 4);

  k_zero8<<<1, 64, 0, stream>>>(cnt);

  dim3 tb(32, 8, 1);
  k_transpose_cvt<<<dim3(DH / 32, DIN / 32, 1), tb, 0, stream>>>(W_in, WtIn, DIN, DH);
  k_transpose_cvt<<<dim3(DMOE / 32, DH / 32, NEXP), tb, 0, stream>>>(W1, Wt1, DH, DMOE);
  k_transpose_cvt<<<dim3(DH / 32, DMOE / 32, NEXP), tb, 0, stream>>>(W2, Wt2, DMOE, DH);
  k_transpose_cvt<<<dim3(DH / 32, DH / 32, 1), tb, 0, stream>>>(W_out, WtOut, DH, DH);
  k_cvt_bf16<<<(NTOK * DIN / 4 + 255) / 256, 256, 0, stream>>>(x, xbf, NTOK * DIN / 4);

  k_gate_prep<<<64, 256, 0, stream>>>(W_in, W_gate, b_in, b_gate, G, cvec);
  k_gating<<<NTOK / 4, 256, 0, stream>>>(x, G, cvec, cnt, list, wlist);
  k_scan<<<1, 64, 0, stream>>>(cnt, offs);

  // h = x @ W_in + b_in  (bf16 out)
  k_gemm128<0><<<dim3(DH / 128, NTOK / 128, 1), 256, 0, stream>>>(
      xbf, WtIn, b_in, hbf, NTOK, DH, DIN);
  // mid = relu(h_gathered @ W1[e] + b1[e])
  k_gemm256<1><<<dim3(DMOE / 256, NTOK / 256, NEXP), 512, 0, stream>>>(
      hbf, Wt1, b1, mid, DMOE, DH, cnt, offs, list, wlist);
  // eout[t][slot] = (mid @ W2[e] + b2[e]) * route_w
  k_gemm256<2><<<dim3(DH / 256, NTOK / 256, NEXP), 512, 0, stream>>>(
      mid, Wt2, b2, eout, DH, DMOE, cnt, offs, list, wlist);
  k_combine<<<NTOK * DH / 4 / 256, 256, 0, stream>>>(eout, moebf);
  // out = moe @ W_out + b_out (fp32 out)
  k_gemm128<3><<<dim3(DH / 128, NTOK / 128, 1), 256, 0, stream>>>(
      moebf, WtOut, b_out, (float*)d_out, NTOK, DH, DH);
}

// Round 7
// 744.259 us; speedup vs baseline: 1.0071x; 1.0071x over previous
//
#include <hip/hip_runtime.h>
#include <hip/hip_bf16.h>

typedef __bf16 bf16_t;
typedef bf16_t bf16x8 __attribute__((ext_vector_type(8)));
typedef bf16_t bf16x4 __attribute__((ext_vector_type(4)));
typedef float f32x4 __attribute__((ext_vector_type(4)));

#define DIN 1024
#define DH 1024
#define DMOE 4096
#define NEXP 8
#define NTOK 4096

__device__ __forceinline__ void gload_lds16(const bf16_t* g, bf16_t* l) {
  __builtin_amdgcn_global_load_lds(
      (const __attribute__((address_space(1))) void*)g,
      (__attribute__((address_space(3))) void*)l, 16, 0, 0);
}

// ---------------- small utility kernels ----------------

__global__ void k_zero8(int* p) {
  if (threadIdx.x < 8) p[threadIdx.x] = 0;
}

// src [b][R][C] f32 -> dst [b][C][R] bf16
__global__ void k_transpose_cvt(const float* __restrict__ src, bf16_t* __restrict__ dst,
                                int R, int C) {
  __shared__ float tile[32][33];
  const size_t mofs = (size_t)blockIdx.z * R * C;
  const float* s = src + mofs;
  bf16_t* d = dst + mofs;
  const int c0 = blockIdx.x * 32, r0 = blockIdx.y * 32;
  const int tx = threadIdx.x, ty = threadIdx.y;
#pragma unroll
  for (int i = 0; i < 32; i += 8)
    tile[ty + i][tx] = s[(size_t)(r0 + ty + i) * C + (c0 + tx)];
  __syncthreads();
#pragma unroll
  for (int i = 0; i < 32; i += 8)
    d[(size_t)(c0 + ty + i) * R + (r0 + tx)] = (bf16_t)tile[tx][ty + i];
}

__global__ void k_cvt_bf16(const float* __restrict__ src, bf16_t* __restrict__ dst, int n4) {
  const int i = blockIdx.x * blockDim.x + threadIdx.x;
  if (i < n4) {
    const float4 v = *(const float4*)(src + (size_t)i * 4);
    bf16x4 o;
    o.x = (bf16_t)v.x; o.y = (bf16_t)v.y; o.z = (bf16_t)v.z; o.w = (bf16_t)v.w;
    *(bf16x4*)(dst + (size_t)i * 4) = o;
  }
}

// G[d][e] = sum_k W_in[d][k] * W_gate[k][e]  (fp64); row d==DH computes c[e] from b_in
__global__ void k_gate_prep(const float* __restrict__ Win, const float* __restrict__ Wgate,
                            const float* __restrict__ b_in, const float* __restrict__ b_gate,
                            double* __restrict__ G, double* __restrict__ cvec) {
  const int lane = threadIdx.x & 63;
  const int wave = (blockIdx.x * blockDim.x + threadIdx.x) >> 6;
  const int nw = (gridDim.x * blockDim.x) >> 6;
  for (int d = wave; d <= DIN; d += nw) {
    const float* row = (d < DIN) ? (Win + (size_t)d * DH) : b_in;
    double acc[8] = {0, 0, 0, 0, 0, 0, 0, 0};
    for (int k = lane; k < DH; k += 64) {
      const double xv = (double)row[k];
      const float* g = Wgate + (size_t)k * NEXP;
#pragma unroll
      for (int ee = 0; ee < 8; ++ee) acc[ee] += xv * (double)g[ee];
    }
#pragma unroll
    for (int ee = 0; ee < 8; ++ee) {
      double a = acc[ee];
      for (int o = 32; o > 0; o >>= 1) a += __shfl_down(a, o);
      acc[ee] = a;
    }
    if (lane == 0) {
      if (d < DIN) {
#pragma unroll
        for (int ee = 0; ee < 8; ++ee) G[(size_t)d * 8 + ee] = acc[ee];
      } else {
#pragma unroll
        for (int ee = 0; ee < 8; ++ee) cvec[ee] = acc[ee] + (double)b_gate[ee];
      }
    }
  }
}

// per token: fp64 logits via fused G, softmax, top-2, scatter into expert lists
__global__ void k_gating(const float* __restrict__ x, const double* __restrict__ G,
                         const double* __restrict__ cvec, int* __restrict__ cnt,
                         int* __restrict__ list, float* __restrict__ wlist) {
  const int lane = threadIdx.x & 63;
  const int t = blockIdx.x * (blockDim.x >> 6) + (threadIdx.x >> 6);
  if (t >= NTOK) return;
  const float* xr = x + (size_t)t * DIN;
  double acc[8] = {0, 0, 0, 0, 0, 0, 0, 0};
  for (int d = lane; d < DIN; d += 64) {
    const double xv = (double)xr[d];
    const double* g = G + (size_t)d * 8;
#pragma unroll
    for (int ee = 0; ee < 8; ++ee) acc[ee] += xv * g[ee];
  }
#pragma unroll
  for (int ee = 0; ee < 8; ++ee) {
    double a = acc[ee];
    for (int o = 32; o > 0; o >>= 1) a += __shfl_down(a, o);
    acc[ee] = a;
  }
  if (lane == 0) {
    double l[8];
#pragma unroll
    for (int ee = 0; ee < 8; ++ee) l[ee] = acc[ee] + cvec[ee];
    double m = l[0];
#pragma unroll
    for (int ee = 1; ee < 8; ++ee) m = fmax(m, l[ee]);
    double p[8];
#pragma unroll
    for (int ee = 0; ee < 8; ++ee) p[ee] = exp(l[ee] - m);
    int i1 = 0;
#pragma unroll
    for (int ee = 1; ee < 8; ++ee)
      if (p[ee] > p[i1]) i1 = ee;
    int i2 = (i1 == 0) ? 1 : 0;
#pragma unroll
    for (int ee = 0; ee < 8; ++ee)
      if (ee != i1 && p[ee] > p[i2]) i2 = ee;
    const double s2 = p[i1] + p[i2];
    const float w1 = (float)(p[i1] / s2);
    const float w2 = (float)(p[i2] / s2);
    int lp = atomicAdd(&cnt[i1], 1);
    list[i1 * NTOK + lp] = t * 2;
    wlist[i1 * NTOK + lp] = w1;
    lp = atomicAdd(&cnt[i2], 1);
    list[i2 * NTOK + lp] = t * 2 + 1;
    wlist[i2 * NTOK + lp] = w2;
  }
}

__global__ void k_scan(const int* __restrict__ cnt, int* __restrict__ offs) {
  if (threadIdx.x == 0) {
    int s = 0;
    for (int e = 0; e < NEXP; ++e) { offs[e] = s; s += cnt[e]; }
    offs[NEXP] = s;
  }
}

// moe_bf16[t] = bf16(eout[t][0] + eout[t][1])   (route weights already applied)
__global__ void k_combine(const float* __restrict__ eout, bf16_t* __restrict__ moebf) {
  const int i = blockIdx.x * blockDim.x + threadIdx.x;
  const int t = i >> 8;
  const int q = (i & 255) * 4;
  const float4 a = *(const float4*)(eout + ((size_t)t * 2) * DH + q);
  const float4 b = *(const float4*)(eout + ((size_t)t * 2 + 1) * DH + q);
  bf16x4 o;
  o.x = (bf16_t)(a.x + b.x); o.y = (bf16_t)(a.y + b.y);
  o.z = (bf16_t)(a.z + b.z); o.w = (bf16_t)(a.w + b.w);
  *(bf16x4*)(moebf + (size_t)t * DH + q) = o;
}

// ---------------- 128x128 BK=32 plain GEMM (round-2 proven), 4 waves ----------------
// MODE 0: plain, bf16 out. MODE 3: plain, fp32 out.
template <int MODE>
__global__ __launch_bounds__(256, 3) void k_gemm128(
    const bf16_t* __restrict__ A, const bf16_t* __restrict__ B,
    const float* __restrict__ bias, void* __restrict__ Cbase,
    int M, int N, int K) {
  const int mblk = blockIdx.y, nblk = blockIdx.x;

  __shared__ bf16_t As[3][128 * 32];
  __shared__ bf16_t Bs[3][128 * 32];

  const int tid = threadIdx.x;
  const int lane = tid & 63;
  const int wid = tid >> 6;
  const int wr = wid >> 1, wc = wid & 1;

  const int srow0 = wid * 32 + (lane >> 2);
  const int srow1 = srow0 + 16;
  const int skcol = (lane & 3) * 8;

  const bf16_t* aptr0 = A + (size_t)(mblk * 128 + srow0) * K + skcol;
  const bf16_t* aptr1 = A + (size_t)(mblk * 128 + srow1) * K + skcol;
  const bf16_t* bptr0 = B + (size_t)(nblk * 128 + srow0) * K + skcol;
  const bf16_t* bptr1 = B + (size_t)(nblk * 128 + srow1) * K + skcol;

  const int ldsOfsA0 = (wid * 32) * 32;
  const int ldsOfsA1 = (wid * 32 + 16) * 32;

  f32x4 acc[4][4] = {};
  const int nkt = K >> 5;

  auto stage = [&](int buf, int kt) {
    const size_t ko = (size_t)kt * 32;
    gload_lds16(aptr0 + ko, &As[buf][ldsOfsA0]);
    gload_lds16(aptr1 + ko, &As[buf][ldsOfsA1]);
    gload_lds16(bptr0 + ko, &Bs[buf][ldsOfsA0]);
    gload_lds16(bptr1 + ko, &Bs[buf][ldsOfsA1]);
  };

  stage(0, 0);
  if (nkt > 1) stage(1, 1);

  int cur = 0;
  for (int kt = 0; kt < nkt; ++kt) {
    int nxt = cur + 2;
    if (nxt >= 3) nxt -= 3;
    if (kt + 2 < nkt) {
      stage(nxt, kt + 2);
      asm volatile("s_waitcnt vmcnt(8)" ::: "memory");
    } else if (kt + 1 < nkt) {
      asm volatile("s_waitcnt vmcnt(4)" ::: "memory");
    } else {
      asm volatile("s_waitcnt vmcnt(0)" ::: "memory");
    }
    __builtin_amdgcn_s_barrier();

    const int fr = lane & 15;
    const int kq = (lane >> 4) * 8;
    bf16x8 af[4], bfr[4];
#pragma unroll
    for (int m = 0; m < 4; ++m)
      af[m] = *(const bf16x8*)&As[cur][(wr * 64 + m * 16 + fr) * 32 + kq];
#pragma unroll
    for (int n = 0; n < 4; ++n)
      bfr[n] = *(const bf16x8*)&Bs[cur][(wc * 64 + n * 16 + fr) * 32 + kq];
#pragma unroll
    for (int m = 0; m < 4; ++m)
#pragma unroll
      for (int n = 0; n < 4; ++n)
        acc[m][n] = __builtin_amdgcn_mfma_f32_16x16x32_bf16(af[m], bfr[n], acc[m][n], 0, 0, 0);

    __builtin_amdgcn_s_barrier();
    cur += 1;
    if (cur >= 3) cur -= 3;
  }

  const int colBase = nblk * 128 + wc * 64 + (lane & 15);
  const int rowBase = mblk * 128 + wr * 64 + ((lane >> 4) << 2);
#pragma unroll
  for (int n = 0; n < 4; ++n) {
    const int c = colBase + n * 16;
    const float bv = bias[c];
#pragma unroll
    for (int m = 0; m < 4; ++m) {
#pragma unroll
      for (int j = 0; j < 4; ++j) {
        const int r = rowBase + m * 16 + j;
        const float v = acc[m][n][j] + bv;
        if constexpr (MODE == 0) {
          ((bf16_t*)Cbase)[(size_t)r * N + c] = (bf16_t)v;
        } else {
          ((float*)Cbase)[(size_t)r * N + c] = v;
        }
      }
    }
  }
}

// ---------------- 256x256 BK=64 expert GEMM, 8 waves, true 8-phase (m201) ----------
// T1 remap + T2 both-sides swizzle + T3/T4 slab-staggered counted vmcnt + T5 setprio.
// __launch_bounds__(512,1): LDS already caps at 1 block/CU; (512,2) was silently
// capping VGPR at 128 (R4-R6: VGPR_Count==128 == cap) and starving the allocator.
// MODE 1: A rows gathered via list (token=entry>>1), relu, bf16 out at rowOff+r
// MODE 2: A = mid + rowOff, fp32 out scattered to eout[entry][*] scaled by wlist
template <int MODE>
__global__ __launch_bounds__(512, 1) void k_gemm256(
    const bf16_t* __restrict__ Abase, const bf16_t* __restrict__ Bbase,
    const float* __restrict__ biasBase, void* __restrict__ Cbase,
    int N, int K,
    const int* __restrict__ cnt, const int* __restrict__ offs,
    const int* __restrict__ listBase, const float* __restrict__ wlistBase) {
  const int e = blockIdx.z;
  const int mtiles = gridDim.y;
  const int hw = blockIdx.y * gridDim.x + blockIdx.x;
  const int cpx = (gridDim.x * gridDim.y) >> 3;
  const int lid = (hw & 7) * cpx + (hw >> 3);
  const int mblk = lid % mtiles;
  const int nblk = lid / mtiles;

  const int Mloc = cnt[e];
  if (mblk * 256 >= Mloc) return;  // uniform early exit, before any barrier
  const bf16_t* B = Bbase + (size_t)e * N * K;
  const float* bias = biasBase + (size_t)e * N;
  const int* myList = listBase + e * NTOK;
  const float* myW = wlistBase + e * NTOK;
  const int rowOff = offs[e];
  const bf16_t* A = (MODE == 2) ? (Abase + (size_t)rowOff * K) : Abase;

  __shared__ bf16_t As[4 * 128 * 64];  // slab (buf*2+h): [128][64]
  __shared__ bf16_t Bs[4 * 128 * 64];

  const int tid = threadIdx.x;
  const int lane = tid & 63;
  const int wid = tid >> 6;  // 0..7
  const int wr = wid >> 2;   // A half owned for reads
  const int wcn = wid & 3;   // N quarter

  // staging source (pre-swizzled col group; both-sides rule #21)
  const int sub_r = lane >> 3;
  const int colg = ((lane & 7) ^ sub_r) * 8;
  uint32_t aoff[2][2], boff[2][2];
#pragma unroll
  for (int h = 0; h < 2; ++h) {
#pragma unroll
    for (int l = 0; l < 2; ++l) {
      const int c = wid * 2 + l;
      int ar = mblk * 256 + h * 128 + c * 8 + sub_r;
      const int br = nblk * 256 + h * 128 + c * 8 + sub_r;
      if (ar > Mloc - 1) ar = Mloc - 1;
      uint32_t arow = (uint32_t)ar;
      if constexpr (MODE == 1) arow = (uint32_t)(myList[ar] >> 1);
      aoff[h][l] = arow * (uint32_t)K + colg;
      boff[h][l] = (uint32_t)br * (uint32_t)K + colg;
    }
  }

  auto stA = [&](int buf, int h, int kt) {
    const uint32_t ko = (uint32_t)kt * 64;
    gload_lds16(A + aoff[h][0] + ko, &As[(buf * 2 + h) * 8192 + (wid * 2 + 0) * 512]);
    gload_lds16(A + aoff[h][1] + ko, &As[(buf * 2 + h) * 8192 + (wid * 2 + 1) * 512]);
  };
  auto stB = [&](int buf, int h, int kt) {
    const uint32_t ko = (uint32_t)kt * 64;
    gload_lds16(B + boff[h][0] + ko, &Bs[(buf * 2 + h) * 8192 + (wid * 2 + 0) * 512]);
    gload_lds16(B + boff[h][1] + ko, &Bs[(buf * 2 + h) * 8192 + (wid * 2 + 1) * 512]);
  };

  const int fr = lane & 15;
  const int s0 = (((lane >> 4) ^ (fr & 7)) << 3);  // kh0 slot; kh1 = s0^32
  const int brow0 = (wcn & 1) * 64;
  const bf16_t* A0 = &As[(0 + wr) * 8192];         // buf0 A slab (this wave)
  const bf16_t* A1 = &As[(2 + wr) * 8192];         // buf1 A slab
  const bf16_t* B0 = &Bs[(0 + (wcn >> 1)) * 8192];
  const bf16_t* B1 = &Bs[(2 + (wcn >> 1)) * 8192];

  f32x4 acc[8][4] = {};
  const int nkt = K >> 6;
  const int iters = nkt >> 1;

  bf16x8 a[4], a2[4], b[4];

  auto rdA = [&](bf16x8* dst, const bf16_t* base, int mo, int s) {
#pragma unroll
    for (int m = 0; m < 4; ++m)
      dst[m] = *(const bf16x8*)&base[((m + mo) * 16 + fr) * 64 + s];
  };
  auto rdB = [&](bf16x8* dst, const bf16_t* base, int s) {
#pragma unroll
    for (int n = 0; n < 4; ++n)
      dst[n] = *(const bf16x8*)&base[(brow0 + n * 16 + fr) * 64 + s];
  };
  auto mfma16 = [&](bf16x8* av, bf16x8* bv, int mo) {
#pragma unroll
    for (int m = 0; m < 4; ++m)
#pragma unroll
      for (int n = 0; n < 4; ++n)
        acc[m + mo][n] =
            __builtin_amdgcn_mfma_f32_16x16x32_bf16(av[m], bv[n], acc[m + mo][n], 0, 0, 0);
  };

#define PHASE_MID()                                        \
  __builtin_amdgcn_s_barrier();                            \
  asm volatile("s_waitcnt lgkmcnt(0)" ::: "memory");       \
  __builtin_amdgcn_sched_barrier(0);                       \
  __builtin_amdgcn_s_setprio(1)
#define PHASE_END()                                        \
  __builtin_amdgcn_s_setprio(0);                           \
  __builtin_amdgcn_s_barrier()

  // prologue: buf0 <- tile0 (all 4 slabs), buf1 <- tile1 first halves (Ah0,Bh0)
  stA(0, 0, 0); stB(0, 0, 0); stA(0, 1, 0); stB(0, 1, 0);
  stA(1, 0, 1); stB(1, 0, 1);
  asm volatile("s_waitcnt vmcnt(4)" ::: "memory");
  __builtin_amdgcn_s_barrier();

  for (int it = 0; it < iters; ++it) {
    const int t0 = 2 * it, t1 = 2 * it + 1;
    const bool pf2 = (t0 + 2 < nkt);
    const bool pf3 = (t1 + 2 < nkt);
    // P1: buf0 kh0 (A m0-3, B); finish staging buf1 <- tile t1 (Ah1,Bh1)
    rdA(a, A0, 0, s0); rdB(b, B0, s0);
    stA(1, 1, t1); stB(1, 1, t1);
    PHASE_MID(); mfma16(a, b, 0); PHASE_END();
    // P2: buf0 kh0 A m4-7
    rdA(a2, A0, 4, s0);
    PHASE_MID(); mfma16(a2, b, 4); PHASE_END();
    // P3: buf0 kh1 (A m0-3, B)
    rdA(a, A0, 0, s0 ^ 32); rdB(b, B0, s0 ^ 32);
    PHASE_MID(); mfma16(a, b, 0); PHASE_END();
    // P4: buf0 kh1 A m4-7; stage buf0.{Ah0,Bh0} <- tile t0+2; checkpoint buf1 staged
    rdA(a2, A0, 4, s0 ^ 32);
    if (pf2) { stA(0, 0, t0 + 2); stB(0, 0, t0 + 2); }
    PHASE_MID(); mfma16(a2, b, 4);
    __builtin_amdgcn_s_setprio(0);
    if (pf2) { asm volatile("s_waitcnt vmcnt(4)" ::: "memory"); }
    else     { asm volatile("s_waitcnt vmcnt(0)" ::: "memory"); }
    __builtin_amdgcn_s_barrier();
    // P5: buf1 kh0 (A m0-3, B); stage buf0.{Ah1,Bh1}
    rdA(a, A1, 0, s0); rdB(b, B1, s0);
    if (pf2) { stA(0, 1, t0 + 2); stB(0, 1, t0 + 2); }
    PHASE_MID(); mfma16(a, b, 0); PHASE_END();
    // P6: buf1 kh0 A m4-7
    rdA(a2, A1, 4, s0);
    PHASE_MID(); mfma16(a2, b, 4); PHASE_END();
    // P7: buf1 kh1 (A m0-3, B)
    rdA(a, A1, 0, s0 ^ 32); rdB(b, B1, s0 ^ 32);
    PHASE_MID(); mfma16(a, b, 0); PHASE_END();
    // P8: buf1 kh1 A m4-7; stage buf1.{Ah0,Bh0} <- tile t1+2; checkpoint buf0 staged
    rdA(a2, A1, 4, s0 ^ 32);
    if (pf3) { stA(1, 0, t1 + 2); stB(1, 0, t1 + 2); }
    PHASE_MID(); mfma16(a2, b, 4);
    __builtin_amdgcn_s_setprio(0);
    if (pf3) { asm volatile("s_waitcnt vmcnt(4)" ::: "memory"); }
    __builtin_amdgcn_s_barrier();
  }
#undef PHASE_MID
#undef PHASE_END

  // epilogue
  const int colBase = nblk * 256 + wcn * 64 + (lane & 15);
  const int rowBase = mblk * 256 + wr * 128 + ((lane >> 4) << 2);
#pragma unroll
  for (int n = 0; n < 4; ++n) {
    const int c = colBase + n * 16;
    const float bv = bias[c];
#pragma unroll
    for (int m = 0; m < 8; ++m) {
#pragma unroll
      for (int j = 0; j < 4; ++j) {
        const int r = rowBase + m * 16 + j;
        float v = acc[m][n][j] + bv;
        if (r < Mloc) {
          if constexpr (MODE == 1) {
            v = fmaxf(v, 0.0f);
            ((bf16_t*)Cbase)[(size_t)(rowOff + r) * N + c] = (bf16_t)v;
          } else {
            const int entry = myList[r];
            const float w = myW[r];
            ((float*)Cbase)[(size_t)entry * DH + c] = v * w;
          }
        }
      }
    }
  }
}

// ---------------- launch ----------------

extern "C" void kernel_launch(void* const* d_in, const int* in_sizes, int n_in,
                              void* d_out, int out_size, void* d_ws, size_t ws_size,
                              hipStream_t stream) {
  const float* x      = (const float*)d_in[0];
  const float* W_in   = (const float*)d_in[1];
  const float* b_in   = (const float*)d_in[2];
  const float* W_gate = (const float*)d_in[3];
  const float* b_gate = (const float*)d_in[4];
  const float* W1     = (const float*)d_in[5];
  const float* b1     = (const float*)d_in[6];
  const float* W2     = (const float*)d_in[7];
  const float* b2     = (const float*)d_in[8];
  const float* W_out  = (const float*)d_in[9];
  const float* b_out  = (const float*)d_in[10];

  char* ws = (char*)d_ws;
  size_t off = 0;
  auto alloc = [&](size_t bytes) -> void* {
    void* p = ws + off;
    off += (bytes + 255) & ~(size_t)255;
    return p;
  };

  bf16_t* WtIn  = (bf16_t*)alloc((size_t)DH * DIN * 2);          // [DH][DIN]
  bf16_t* Wt1   = (bf16_t*)alloc((size_t)NEXP * DMOE * DH * 2);  // [E][DMOE][DH]
  bf16_t* Wt2   = (bf16_t*)alloc((size_t)NEXP * DH * DMOE * 2);  // [E][DH][DMOE]
  bf16_t* WtOut = (bf16_t*)alloc((size_t)DH * DH * 2);           // [DOUT][DH]
  bf16_t* xbf   = (bf16_t*)alloc((size_t)NTOK * DIN * 2);
  bf16_t* hbf   = (bf16_t*)alloc((size_t)NTOK * DH * 2);
  bf16_t* mid   = (bf16_t*)alloc((size_t)2 * NTOK * DMOE * 2);   // [2N][DMOE]
  float*  eout  = (float*)alloc((size_t)2 * NTOK * DH * 4);      // [2N][DH] (t*2+slot)
  bf16_t* moebf = (bf16_t*)alloc((size_t)NTOK * DH * 2);
  double* G     = (double*)alloc((size_t)DIN * 8 * 8);
  double* cvec  = (double*)alloc(8 * 8);
  int*    cnt   = (int*)alloc(NEXP * 4);
  int*    offs  = (int*)alloc((NEXP + 1) * 4);
  int*    list  = (int*)alloc((size_t)NEXP * NTOK * 4);
  float*  wlist = (float*)alloc((size_t)NEXP * NTOK * 4);

  k_zero8<<<1, 64, 0, stream>>>(cnt);

  dim3 tb(32, 8, 1);
  k_transpose_cvt<<<dim3(DH / 32, DIN / 32, 1), tb, 0, stream>>>(W_in, WtIn, DIN, DH);
  k_transpose_cvt<<<dim3(DMOE / 32, DH / 32, NEXP), tb, 0, stream>>>(W1, Wt1, DH, DMOE);
  k_transpose_cvt<<<dim3(DH / 32, DMOE / 32, NEXP), tb, 0, stream>>>(W2, Wt2, DMOE, DH);
  k_transpose_cvt<<<dim3(DH / 32, DH / 32, 1), tb, 0, stream>>>(W_out, WtOut, DH, DH);
  k_cvt_bf16<<<(NTOK * DIN / 4 + 255) / 256, 256, 0, stream>>>(x, xbf, NTOK * DIN / 4);

  k_gate_prep<<<64, 256, 0, stream>>>(W_in, W_gate, b_in, b_gate, G, cvec);
  k_gating<<<NTOK / 4, 256, 0, stream>>>(x, G, cvec, cnt, list, wlist);
  k_scan<<<1, 64, 0, stream>>>(cnt, offs);

  // h = x @ W_in + b_in  (bf16 out)
  k_gemm128<0><<<dim3(DH / 128, NTOK / 128, 1), 256, 0, stream>>>(
      xbf, WtIn, b_in, hbf, NTOK, DH, DIN);
  // mid = relu(h_gathered @ W1[e] + b1[e])
  k_gemm256<1><<<dim3(DMOE / 256, NTOK / 256, NEXP), 512, 0, stream>>>(
      hbf, Wt1, b1, mid, DMOE, DH, cnt, offs, list, wlist);
  // eout[t][slot] = (mid @ W2[e] + b2[e]) * route_w
  k_gemm256<2><<<dim3(DH / 256, NTOK / 256, NEXP), 512, 0, stream>>>(
      mid, Wt2, b2, eout, DH, DMOE, cnt, offs, list, wlist);
  k_combine<<<NTOK * DH / 4 / 256, 256, 0, stream>>>(eout, moebf);
  // out = moe @ W_out + b_out (fp32 out)
  k_gemm128<3><<<dim3(DH / 128, NTOK / 128, 1), 256, 0, stream>>>(
      moebf, WtOut, b_out, (float*)d_out, NTOK, DH, DH);
}

// Round 8
// 632.838 us; speedup vs baseline: 1.1844x; 1.1761x over previous
//
#include <hip/hip_runtime.h>
#include <hip/hip_bf16.h>

typedef __bf16 bf16_t;
typedef bf16_t bf16x8 __attribute__((ext_vector_type(8)));
typedef bf16_t bf16x4 __attribute__((ext_vector_type(4)));
typedef float f32x4 __attribute__((ext_vector_type(4)));

#define DIN 1024
#define DH 1024
#define DMOE 4096
#define NEXP 8
#define NTOK 4096

__device__ __forceinline__ void gload_lds16(const bf16_t* g, bf16_t* l) {
  __builtin_amdgcn_global_load_lds(
      (const __attribute__((address_space(1))) void*)g,
      (__attribute__((address_space(3))) void*)l, 16, 0, 0);
}

// ---------------- small utility kernels ----------------

__global__ void k_zero8(int* p) {
  if (threadIdx.x < 8) p[threadIdx.x] = 0;
}

// src [b][R][C] f32 -> dst [b][C][R] bf16.  64x64 tile, float4 loads, bf16x4 stores.
__global__ void k_transpose_cvt(const float* __restrict__ src, bf16_t* __restrict__ dst,
                                int R, int C) {
  __shared__ float tile[64][65];
  const size_t mofs = (size_t)blockIdx.z * R * C;
  const float* s = src + mofs;
  bf16_t* d = dst + mofs;
  const int c0 = blockIdx.x * 64, r0 = blockIdx.y * 64;
  const int t = threadIdx.x;
  const int rr = t >> 4;          // 0..15
  const int cc = (t & 15) << 2;   // 0,4,..,60
#pragma unroll
  for (int i = 0; i < 64; i += 16) {
    const float4 v = *(const float4*)&s[(size_t)(r0 + rr + i) * C + c0 + cc];
    tile[rr + i][cc + 0] = v.x;
    tile[rr + i][cc + 1] = v.y;
    tile[rr + i][cc + 2] = v.z;
    tile[rr + i][cc + 3] = v.w;
  }
  __syncthreads();
  const int oc = t >> 4;          // out-row (= src col) block 0..15
  const int orr = (t & 15) << 2;  // src row quad
#pragma unroll
  for (int i = 0; i < 64; i += 16) {
    bf16x4 o;
    o.x = (bf16_t)tile[orr + 0][oc + i];
    o.y = (bf16_t)tile[orr + 1][oc + i];
    o.z = (bf16_t)tile[orr + 2][oc + i];
    o.w = (bf16_t)tile[orr + 3][oc + i];
    *(bf16x4*)&d[(size_t)(c0 + oc + i) * R + r0 + orr] = o;
  }
}

__global__ void k_cvt_bf16(const float* __restrict__ src, bf16_t* __restrict__ dst, int n4) {
  const int i = blockIdx.x * blockDim.x + threadIdx.x;
  if (i < n4) {
    const float4 v = *(const float4*)(src + (size_t)i * 4);
    bf16x4 o;
    o.x = (bf16_t)v.x; o.y = (bf16_t)v.y; o.z = (bf16_t)v.z; o.w = (bf16_t)v.w;
    *(bf16x4*)(dst + (size_t)i * 4) = o;
  }
}

// G[d][e] = sum_k W_in[d][k] * W_gate[k][e]  (fp64); row d==DH computes c[e] from b_in
__global__ void k_gate_prep(const float* __restrict__ Win, const float* __restrict__ Wgate,
                            const float* __restrict__ b_in, const float* __restrict__ b_gate,
                            double* __restrict__ G, double* __restrict__ cvec) {
  const int lane = threadIdx.x & 63;
  const int wave = (blockIdx.x * blockDim.x + threadIdx.x) >> 6;
  const int nw = (gridDim.x * blockDim.x) >> 6;
  for (int d = wave; d <= DIN; d += nw) {
    const float* row = (d < DIN) ? (Win + (size_t)d * DH) : b_in;
    double acc[8] = {0, 0, 0, 0, 0, 0, 0, 0};
    for (int k = lane; k < DH; k += 64) {
      const double xv = (double)row[k];
      const float* g = Wgate + (size_t)k * NEXP;
#pragma unroll
      for (int ee = 0; ee < 8; ++ee) acc[ee] += xv * (double)g[ee];
    }
#pragma unroll
    for (int ee = 0; ee < 8; ++ee) {
      double a = acc[ee];
      for (int o = 32; o > 0; o >>= 1) a += __shfl_down(a, o);
      acc[ee] = a;
    }
    if (lane == 0) {
      if (d < DIN) {
#pragma unroll
        for (int ee = 0; ee < 8; ++ee) G[(size_t)d * 8 + ee] = acc[ee];
      } else {
#pragma unroll
        for (int ee = 0; ee < 8; ++ee) cvec[ee] = acc[ee] + (double)b_gate[ee];
      }
    }
  }
}

// per token: fp64 logits via fused G, softmax, top-2, scatter into expert lists
__global__ void k_gating(const float* __restrict__ x, const double* __restrict__ G,
                         const double* __restrict__ cvec, int* __restrict__ cnt,
                         int* __restrict__ list, float* __restrict__ wlist) {
  const int lane = threadIdx.x & 63;
  const int t = blockIdx.x * (blockDim.x >> 6) + (threadIdx.x >> 6);
  if (t >= NTOK) return;
  const float* xr = x + (size_t)t * DIN;
  double acc[8] = {0, 0, 0, 0, 0, 0, 0, 0};
  for (int d = lane; d < DIN; d += 64) {
    const double xv = (double)xr[d];
    const double* g = G + (size_t)d * 8;
#pragma unroll
    for (int ee = 0; ee < 8; ++ee) acc[ee] += xv * g[ee];
  }
#pragma unroll
  for (int ee = 0; ee < 8; ++ee) {
    double a = acc[ee];
    for (int o = 32; o > 0; o >>= 1) a += __shfl_down(a, o);
    acc[ee] = a;
  }
  if (lane == 0) {
    double l[8];
#pragma unroll
    for (int ee = 0; ee < 8; ++ee) l[ee] = acc[ee] + cvec[ee];
    double m = l[0];
#pragma unroll
    for (int ee = 1; ee < 8; ++ee) m = fmax(m, l[ee]);
    double p[8];
#pragma unroll
    for (int ee = 0; ee < 8; ++ee) p[ee] = exp(l[ee] - m);
    int i1 = 0;
#pragma unroll
    for (int ee = 1; ee < 8; ++ee)
      if (p[ee] > p[i1]) i1 = ee;
    int i2 = (i1 == 0) ? 1 : 0;
#pragma unroll
    for (int ee = 0; ee < 8; ++ee)
      if (ee != i1 && p[ee] > p[i2]) i2 = ee;
    const double s2 = p[i1] + p[i2];
    const float w1 = (float)(p[i1] / s2);
    const float w2 = (float)(p[i2] / s2);
    int lp = atomicAdd(&cnt[i1], 1);
    list[i1 * NTOK + lp] = t * 2;
    wlist[i1 * NTOK + lp] = w1;
    lp = atomicAdd(&cnt[i2], 1);
    list[i2 * NTOK + lp] = t * 2 + 1;
    wlist[i2 * NTOK + lp] = w2;
  }
}

__global__ void k_scan(const int* __restrict__ cnt, int* __restrict__ offs) {
  if (threadIdx.x == 0) {
    int s = 0;
    for (int e = 0; e < NEXP; ++e) { offs[e] = s; s += cnt[e]; }
    offs[NEXP] = s;
  }
}

// moe_bf16[t] = bf16(eout[t][0] + eout[t][1])   (route weights already applied)
__global__ void k_combine(const float* __restrict__ eout, bf16_t* __restrict__ moebf) {
  const int i = blockIdx.x * blockDim.x + threadIdx.x;
  const int t = i >> 8;
  const int q = (i & 255) * 4;
  const float4 a = *(const float4*)(eout + ((size_t)t * 2) * DH + q);
  const float4 b = *(const float4*)(eout + ((size_t)t * 2 + 1) * DH + q);
  bf16x4 o;
  o.x = (bf16_t)(a.x + b.x); o.y = (bf16_t)(a.y + b.y);
  o.z = (bf16_t)(a.z + b.z); o.w = (bf16_t)(a.w + b.w);
  *(bf16x4*)(moebf + (size_t)t * DH + q) = o;
}

// ---------------- unified 128x128 BK=64 GEMM, 4 waves, 2-phase (m230-V0) ----------
// 2 LDS buffers (64 KB -> 2 blocks/CU TLP). One __syncthreads per K-tile (its
// vmcnt(0)+lgkmcnt(0) drain IS the m230 recipe; ds_read->MFMA waits are the
// compiler's fine-grained ones). XOR-swizzled LDS (both-sides, proven R4-R7:
// BANK_CONFLICT=0): source col pre-swizzled, read slot = (kq ^ (row&7)).
// MODE 0: plain, bf16 out. MODE 1: gather rows via list, relu, bf16 @rowOff+r.
// MODE 2: A = mid+rowOff, fp32 scattered to eout[entry] * wlist. MODE 3: fp32 out.
template <int MODE>
__global__ __launch_bounds__(256, 2) void k_gemm(
    const bf16_t* __restrict__ Abase, const bf16_t* __restrict__ Bbase,
    const float* __restrict__ biasBase, void* __restrict__ Cbase,
    int M, int N, int K,
    const int* __restrict__ cnt, const int* __restrict__ offs,
    const int* __restrict__ listBase, const float* __restrict__ wlistBase) {
  const int e = blockIdx.z;
  const int mblk = blockIdx.y, nblk = blockIdx.x;
  int Mloc = M;
  const bf16_t* A = Abase;
  const bf16_t* B = Bbase;
  const float* bias = biasBase;
  const int* myList = nullptr;
  const float* myW = nullptr;
  int rowOff = 0;
  if constexpr (MODE == 1 || MODE == 2) {
    Mloc = cnt[e];
    if (mblk * 128 >= Mloc) return;  // uniform early exit, before any barrier
    B = Bbase + (size_t)e * N * K;
    bias = biasBase + (size_t)e * N;
    myList = listBase + e * NTOK;
    myW = wlistBase + e * NTOK;
    rowOff = offs[e];
    if constexpr (MODE == 2) A = Abase + (size_t)rowOff * K;
  }

  __shared__ bf16_t As[2][128 * 64];
  __shared__ bf16_t Bs[2][128 * 64];

  const int tid = threadIdx.x;
  const int lane = tid & 63;
  const int wid = tid >> 6;  // 0..3
  const int wr = wid >> 1, wc = wid & 1;

  // staging: chunk = 8 rows x 64 cols (one gload_lds); 4 A-chunks + 4 B-chunks/wave
  const int sub_r = lane >> 3;                  // row within chunk 0..7
  const int colg = ((lane & 7) ^ sub_r) * 8;    // pre-swizzled source col (rule #21)
  uint32_t aoff[4], boff[4];
#pragma unroll
  for (int l = 0; l < 4; ++l) {
    const int c = wid * 4 + l;  // chunk 0..15
    int ar = mblk * 128 + c * 8 + sub_r;
    const int br = nblk * 128 + c * 8 + sub_r;
    if constexpr (MODE == 1 || MODE == 2) {
      if (ar > Mloc - 1) ar = Mloc - 1;
    }
    uint32_t arow = (uint32_t)ar;
    if constexpr (MODE == 1) arow = (uint32_t)(myList[ar] >> 1);
    aoff[l] = arow * (uint32_t)K + colg;
    boff[l] = (uint32_t)br * (uint32_t)K + colg;
  }

  auto stage = [&](int buf, int kt) {
    const uint32_t ko = (uint32_t)kt * 64;
#pragma unroll
    for (int l = 0; l < 4; ++l)
      gload_lds16(A + aoff[l] + ko, &As[buf][(wid * 4 + l) * 512]);
#pragma unroll
    for (int l = 0; l < 4; ++l)
      gload_lds16(B + boff[l] + ko, &Bs[buf][(wid * 4 + l) * 512]);
  };

  const int fr = lane & 15;
  const int s0 = (((lane >> 4) ^ (fr & 7)) << 3);  // kh0 slot; kh1 = s0^32
  const int s1 = s0 ^ 32;

  f32x4 acc[4][4] = {};
  const int nkt = K >> 6;

  stage(0, 0);
  __syncthreads();

  int cur = 0;
  for (int kt = 0; kt < nkt; ++kt) {
    if (kt + 1 < nkt) stage(cur ^ 1, kt + 1);  // prefetch next tile (covered by MFMAs)
    bf16x8 a0[4], b0[4], a1[4], b1[4];
#pragma unroll
    for (int m = 0; m < 4; ++m)
      a0[m] = *(const bf16x8*)&As[cur][(wr * 64 + m * 16 + fr) * 64 + s0];
#pragma unroll
    for (int n = 0; n < 4; ++n)
      b0[n] = *(const bf16x8*)&Bs[cur][(wc * 64 + n * 16 + fr) * 64 + s0];
#pragma unroll
    for (int m = 0; m < 4; ++m)
      a1[m] = *(const bf16x8*)&As[cur][(wr * 64 + m * 16 + fr) * 64 + s1];
#pragma unroll
    for (int n = 0; n < 4; ++n)
      b1[n] = *(const bf16x8*)&Bs[cur][(wc * 64 + n * 16 + fr) * 64 + s1];
#pragma unroll
    for (int m = 0; m < 4; ++m)
#pragma unroll
      for (int n = 0; n < 4; ++n)
        acc[m][n] = __builtin_amdgcn_mfma_f32_16x16x32_bf16(a0[m], b0[n], acc[m][n], 0, 0, 0);
#pragma unroll
    for (int m = 0; m < 4; ++m)
#pragma unroll
      for (int n = 0; n < 4; ++n)
        acc[m][n] = __builtin_amdgcn_mfma_f32_16x16x32_bf16(a1[m], b1[n], acc[m][n], 0, 0, 0);
    __syncthreads();  // drains vmcnt(0)+lgkmcnt(0): next tile staged, this buf free
    cur ^= 1;
  }

  // epilogue: C row = (lane>>4)*4 + j (+16m), col = lane&15 (+16n)  [m89-verified]
  const int colBase = nblk * 128 + wc * 64 + (lane & 15);
  const int rowBase = mblk * 128 + wr * 64 + ((lane >> 4) << 2);
#pragma unroll
  for (int n = 0; n < 4; ++n) {
    const int c = colBase + n * 16;
    const float bv = bias[c];
#pragma unroll
    for (int m = 0; m < 4; ++m) {
#pragma unroll
      for (int j = 0; j < 4; ++j) {
        const int r = rowBase + m * 16 + j;
        float v = acc[m][n][j] + bv;
        if constexpr (MODE == 0) {
          ((bf16_t*)Cbase)[(size_t)r * N + c] = (bf16_t)v;
        } else if constexpr (MODE == 1) {
          if (r < Mloc) {
            v = fmaxf(v, 0.0f);
            ((bf16_t*)Cbase)[(size_t)(rowOff + r) * N + c] = (bf16_t)v;
          }
        } else if constexpr (MODE == 2) {
          if (r < Mloc) {
            const int entry = myList[r];
            const float w = myW[r];
            ((float*)Cbase)[(size_t)entry * DH + c] = v * w;
          }
        } else {
          ((float*)Cbase)[(size_t)r * N + c] = v;
        }
      }
    }
  }
}

// ---------------- launch ----------------

extern "C" void kernel_launch(void* const* d_in, const int* in_sizes, int n_in,
                              void* d_out, int out_size, void* d_ws, size_t ws_size,
                              hipStream_t stream) {
  const float* x      = (const float*)d_in[0];
  const float* W_in   = (const float*)d_in[1];
  const float* b_in   = (const float*)d_in[2];
  const float* W_gate = (const float*)d_in[3];
  const float* b_gate = (const float*)d_in[4];
  const float* W1     = (const float*)d_in[5];
  const float* b1     = (const float*)d_in[6];
  const float* W2     = (const float*)d_in[7];
  const float* b2     = (const float*)d_in[8];
  const float* W_out  = (const float*)d_in[9];
  const float* b_out  = (const float*)d_in[10];

  char* ws = (char*)d_ws;
  size_t off = 0;
  auto alloc = [&](size_t bytes) -> void* {
    void* p = ws + off;
    off += (bytes + 255) & ~(size_t)255;
    return p;
  };

  bf16_t* WtIn  = (bf16_t*)alloc((size_t)DH * DIN * 2);          // [DH][DIN]
  bf16_t* Wt1   = (bf16_t*)alloc((size_t)NEXP * DMOE * DH * 2);  // [E][DMOE][DH]
  bf16_t* Wt2   = (bf16_t*)alloc((size_t)NEXP * DH * DMOE * 2);  // [E][DH][DMOE]
  bf16_t* WtOut = (bf16_t*)alloc((size_t)DH * DH * 2);           // [DOUT][DH]
  bf16_t* xbf   = (bf16_t*)alloc((size_t)NTOK * DIN * 2);
  bf16_t* hbf   = (bf16_t*)alloc((size_t)NTOK * DH * 2);
  bf16_t* mid   = (bf16_t*)alloc((size_t)2 * NTOK * DMOE * 2);   // [2N][DMOE]
  float*  eout  = (float*)alloc((size_t)2 * NTOK * DH * 4);      // [2N][DH] (t*2+slot)
  bf16_t* moebf = (bf16_t*)alloc((size_t)NTOK * DH * 2);
  double* G     = (double*)alloc((size_t)DIN * 8 * 8);
  double* cvec  = (double*)alloc(8 * 8);
  int*    cnt   = (int*)alloc(NEXP * 4);
  int*    offs  = (int*)alloc((NEXP + 1) * 4);
  int*    list  = (int*)alloc((size_t)NEXP * NTOK * 4);
  float*  wlist = (float*)alloc((size_t)NEXP * NTOK * 4);

  k_zero8<<<1, 64, 0, stream>>>(cnt);

  k_transpose_cvt<<<dim3(DH / 64, DIN / 64, 1), 256, 0, stream>>>(W_in, WtIn, DIN, DH);
  k_transpose_cvt<<<dim3(DMOE / 64, DH / 64, NEXP), 256, 0, stream>>>(W1, Wt1, DH, DMOE);
  k_transpose_cvt<<<dim3(DH / 64, DMOE / 64, NEXP), 256, 0, stream>>>(W2, Wt2, DMOE, DH);
  k_transpose_cvt<<<dim3(DH / 64, DH / 64, 1), 256, 0, stream>>>(W_out, WtOut, DH, DH);
  k_cvt_bf16<<<(NTOK * DIN / 4 + 255) / 256, 256, 0, stream>>>(x, xbf, NTOK * DIN / 4);

  k_gate_prep<<<64, 256, 0, stream>>>(W_in, W_gate, b_in, b_gate, G, cvec);
  k_gating<<<NTOK / 4, 256, 0, stream>>>(x, G, cvec, cnt, list, wlist);
  k_scan<<<1, 64, 0, stream>>>(cnt, offs);

  // h = x @ W_in + b_in  (bf16 out)
  k_gemm<0><<<dim3(DH / 128, NTOK / 128, 1), 256, 0, stream>>>(
      xbf, WtIn, b_in, hbf, NTOK, DH, DIN, nullptr, nullptr, nullptr, nullptr);
  // mid = relu(h_gathered @ W1[e] + b1[e])
  k_gemm<1><<<dim3(DMOE / 128, NTOK / 128, NEXP), 256, 0, stream>>>(
      hbf, Wt1, b1, mid, NTOK, DMOE, DH, cnt, offs, list, wlist);
  // eout[t][slot] = (mid @ W2[e] + b2[e]) * route_w
  k_gemm<2><<<dim3(DH / 128, NTOK / 128, NEXP), 256, 0, stream>>>(
      mid, Wt2, b2, eout, NTOK, DH, DMOE, cnt, offs, list, wlist);
  k_combine<<<NTOK * DH / 4 / 256, 256, 0, stream>>>(eout, moebf);
  // out = moe @ W_out + b_out (fp32 out)
  k_gemm<3><<<dim3(DH / 128, NTOK / 128, 1), 256, 0, stream>>>(
      moebf, WtOut, b_out, (float*)d_out, NTOK, DH, DH, nullptr, nullptr, nullptr, nullptr);
}

// Round 10
// 573.511 us; speedup vs baseline: 1.3070x; 1.1034x over previous
//
#include <hip/hip_runtime.h>
#include <hip/hip_bf16.h>

typedef __bf16 bf16_t;
typedef bf16_t bf16x8 __attribute__((ext_vector_type(8)));
typedef bf16_t bf16x4 __attribute__((ext_vector_type(4)));
typedef float f32x4 __attribute__((ext_vector_type(4)));

#define DIN 1024
#define DH 1024
#define DMOE 4096
#define NEXP 8
#define NTOK 4096

__device__ __forceinline__ void gload_lds16(const bf16_t* g, bf16_t* l) {
  __builtin_amdgcn_global_load_lds(
      (const __attribute__((address_space(1))) void*)g,
      (__attribute__((address_space(3))) void*)l, 16, 0, 0);
}

// ---------------- small utility kernels ----------------

__global__ void k_zero8(int* p) {
  if (threadIdx.x < 8) p[threadIdx.x] = 0;
}

// src [b][R][C] f32 -> dst [b][C][R] bf16.  64x64 tile, float4 loads, bf16x4 stores.
__global__ void k_transpose_cvt(const float* __restrict__ src, bf16_t* __restrict__ dst,
                                int R, int C) {
  __shared__ float tile[64][65];
  const size_t mofs = (size_t)blockIdx.z * R * C;
  const float* s = src + mofs;
  bf16_t* d = dst + mofs;
  const int c0 = blockIdx.x * 64, r0 = blockIdx.y * 64;
  const int t = threadIdx.x;
  const int rr = t >> 4;          // 0..15
  const int cc = (t & 15) << 2;   // 0,4,..,60
#pragma unroll
  for (int i = 0; i < 64; i += 16) {
    const float4 v = *(const float4*)&s[(size_t)(r0 + rr + i) * C + c0 + cc];
    tile[rr + i][cc + 0] = v.x;
    tile[rr + i][cc + 1] = v.y;
    tile[rr + i][cc + 2] = v.z;
    tile[rr + i][cc + 3] = v.w;
  }
  __syncthreads();
  const int oc = t >> 4;          // out-row (= src col) block 0..15
  const int orr = (t & 15) << 2;  // src row quad
#pragma unroll
  for (int i = 0; i < 64; i += 16) {
    bf16x4 o;
    o.x = (bf16_t)tile[orr + 0][oc + i];
    o.y = (bf16_t)tile[orr + 1][oc + i];
    o.z = (bf16_t)tile[orr + 2][oc + i];
    o.w = (bf16_t)tile[orr + 3][oc + i];
    *(bf16x4*)&d[(size_t)(c0 + oc + i) * R + r0 + orr] = o;
  }
}

__global__ void k_cvt_bf16(const float* __restrict__ src, bf16_t* __restrict__ dst, int n4) {
  const int i = blockIdx.x * blockDim.x + threadIdx.x;
  if (i < n4) {
    const float4 v = *(const float4*)(src + (size_t)i * 4);
    bf16x4 o;
    o.x = (bf16_t)v.x; o.y = (bf16_t)v.y; o.z = (bf16_t)v.z; o.w = (bf16_t)v.w;
    *(bf16x4*)(dst + (size_t)i * 4) = o;
  }
}

// G[d][e] = sum_k W_in[d][k] * W_gate[k][e]  (fp64); row d==DH computes c[e] from b_in
__global__ void k_gate_prep(const float* __restrict__ Win, const float* __restrict__ Wgate,
                            const float* __restrict__ b_in, const float* __restrict__ b_gate,
                            double* __restrict__ G, double* __restrict__ cvec) {
  const int lane = threadIdx.x & 63;
  const int wave = (blockIdx.x * blockDim.x + threadIdx.x) >> 6;
  const int nw = (gridDim.x * blockDim.x) >> 6;
  for (int d = wave; d <= DIN; d += nw) {
    const float* row = (d < DIN) ? (Win + (size_t)d * DH) : b_in;
    double acc[8] = {0, 0, 0, 0, 0, 0, 0, 0};
    for (int k = lane; k < DH; k += 64) {
      const double xv = (double)row[k];
      const float* g = Wgate + (size_t)k * NEXP;
#pragma unroll
      for (int ee = 0; ee < 8; ++ee) acc[ee] += xv * (double)g[ee];
    }
#pragma unroll
    for (int ee = 0; ee < 8; ++ee) {
      double a = acc[ee];
      for (int o = 32; o > 0; o >>= 1) a += __shfl_down(a, o);
      acc[ee] = a;
    }
    if (lane == 0) {
      if (d < DIN) {
#pragma unroll
        for (int ee = 0; ee < 8; ++ee) G[(size_t)d * 8 + ee] = acc[ee];
      } else {
#pragma unroll
        for (int ee = 0; ee < 8; ++ee) cvec[ee] = acc[ee] + (double)b_gate[ee];
      }
    }
  }
}

// per token: fp64 logits via fused G, softmax, top-2, scatter into expert lists
__global__ void k_gating(const float* __restrict__ x, const double* __restrict__ G,
                         const double* __restrict__ cvec, int* __restrict__ cnt,
                         int* __restrict__ list, float* __restrict__ wlist) {
  const int lane = threadIdx.x & 63;
  const int t = blockIdx.x * (blockDim.x >> 6) + (threadIdx.x >> 6);
  if (t >= NTOK) return;
  const float* xr = x + (size_t)t * DIN;
  double acc[8] = {0, 0, 0, 0, 0, 0, 0, 0};
  for (int d = lane; d < DIN; d += 64) {
    const double xv = (double)xr[d];
    const double* g = G + (size_t)d * 8;
#pragma unroll
    for (int ee = 0; ee < 8; ++ee) acc[ee] += xv * g[ee];
  }
#pragma unroll
  for (int ee = 0; ee < 8; ++ee) {
    double a = acc[ee];
    for (int o = 32; o > 0; o >>= 1) a += __shfl_down(a, o);
    acc[ee] = a;
  }
  if (lane == 0) {
    double l[8];
#pragma unroll
    for (int ee = 0; ee < 8; ++ee) l[ee] = acc[ee] + cvec[ee];
    double m = l[0];
#pragma unroll
    for (int ee = 1; ee < 8; ++ee) m = fmax(m, l[ee]);
    double p[8];
#pragma unroll
    for (int ee = 0; ee < 8; ++ee) p[ee] = exp(l[ee] - m);
    int i1 = 0;
#pragma unroll
    for (int ee = 1; ee < 8; ++ee)
      if (p[ee] > p[i1]) i1 = ee;
    int i2 = (i1 == 0) ? 1 : 0;
#pragma unroll
    for (int ee = 0; ee < 8; ++ee)
      if (ee != i1 && p[ee] > p[i2]) i2 = ee;
    const double s2 = p[i1] + p[i2];
    const float w1 = (float)(p[i1] / s2);
    const float w2 = (float)(p[i2] / s2);
    int lp = atomicAdd(&cnt[i1], 1);
    list[i1 * NTOK + lp] = t * 2;
    wlist[i1 * NTOK + lp] = w1;
    lp = atomicAdd(&cnt[i2], 1);
    list[i2 * NTOK + lp] = t * 2 + 1;
    wlist[i2 * NTOK + lp] = w2;
  }
}

__global__ void k_scan(const int* __restrict__ cnt, int* __restrict__ offs) {
  if (threadIdx.x == 0) {
    int s = 0;
    for (int e = 0; e < NEXP; ++e) { offs[e] = s; s += cnt[e]; }
    offs[NEXP] = s;
  }
}

// moe_bf16[t] = bf16(eout[t][0] + eout[t][1])   (route weights already applied)
__global__ void k_combine(const float* __restrict__ eout, bf16_t* __restrict__ moebf) {
  const int i = blockIdx.x * blockDim.x + threadIdx.x;
  const int t = i >> 8;
  const int q = (i & 255) * 4;
  const float4 a = *(const float4*)(eout + ((size_t)t * 2) * DH + q);
  const float4 b = *(const float4*)(eout + ((size_t)t * 2 + 1) * DH + q);
  bf16x4 o;
  o.x = (bf16_t)(a.x + b.x); o.y = (bf16_t)(a.y + b.y);
  o.z = (bf16_t)(a.z + b.z); o.w = (bf16_t)(a.w + b.w);
  *(bf16x4*)(moebf + (size_t)t * DH + q) = o;
}

// ---------------- 128x128 BK=32 bf16 MFMA GEMM, 4 waves (R2 structure + swizzle) ----
// 3 LDS buffers, depth-2 prefetch via global_load_lds, raw s_barrier + counted vmcnt.
// NEW vs R2: conflict-free LDS. Row = 64B = 4 x 16B slots; phys_slot = s ^ ((row>>1)&3)
// -> each 16-lane fragment group spreads over 8 banks (residual 2-way = free, m136).
// Both-sides (rule #21): source col pre-swizzled, read slot swizzled with same involution.
// MODE 0: plain, bf16 out (h)
// MODE 1: expert, A rows gathered via list (token = entry>>1), relu, bf16 out at rowOff+r
// MODE 2: expert, A = mid + rowOff, out fp32 scattered to eout[entry][*] scaled by wlist
// MODE 3: plain, fp32 out (final)
template <int MODE>
__global__ __launch_bounds__(256, 3) void k_gemm(
    const bf16_t* __restrict__ Abase, const bf16_t* __restrict__ Bbase,
    const float* __restrict__ biasBase, void* __restrict__ Cbase,
    int M, int N, int K,
    const int* __restrict__ cnt, const int* __restrict__ offs,
    const int* __restrict__ listBase, const float* __restrict__ wlistBase) {
  const int e = blockIdx.z;
  const int mblk = blockIdx.y, nblk = blockIdx.x;
  int Mloc = M;
  const bf16_t* A = Abase;
  const bf16_t* B = Bbase;
  const float* bias = biasBase;
  const int* myList = nullptr;
  const float* myW = nullptr;
  int rowOff = 0;
  if constexpr (MODE == 1 || MODE == 2) {
    Mloc = cnt[e];
    if (mblk * 128 >= Mloc) return;  // uniform early exit, before any barrier
    B = Bbase + (size_t)e * N * K;
    bias = biasBase + (size_t)e * N;
    myList = listBase + e * NTOK;
    myW = wlistBase + e * NTOK;
    rowOff = offs[e];
    if constexpr (MODE == 2) A = Abase + (size_t)rowOff * K;
  }

  __shared__ bf16_t As[3][128 * 32];
  __shared__ bf16_t Bs[3][128 * 32];

  const int tid = threadIdx.x;
  const int lane = tid & 63;
  const int wid = tid >> 6;
  const int wr = wid >> 1, wc = wid & 1;

  // staging: each wave stages rows [wid*32, wid*32+32) of A and Bt, 16B/lane.
  // Source col slot pre-swizzled: lane's LDS phys slot is (lane&3); it must hold
  // global slot (lane&3) ^ ((row>>1)&3) = (lane&3) ^ ((lane>>3)&3)  [row=lane>>2 within
  // chunk; both 16-row chunks give the same (row>>1)&3 since bases are mult. of 32].
  const int srow0 = wid * 32 + (lane >> 2);
  const int srow1 = srow0 + 16;
  const int skcol = ((lane & 3) ^ ((lane >> 3) & 3)) * 8;

  int ar0 = mblk * 128 + srow0;
  int ar1 = mblk * 128 + srow1;
  if constexpr (MODE == 1 || MODE == 2) {
    if (ar0 > Mloc - 1) ar0 = Mloc - 1;
    if (ar1 > Mloc - 1) ar1 = Mloc - 1;
  }
  size_t arow0 = (size_t)ar0, arow1 = (size_t)ar1;
  if constexpr (MODE == 1) {
    arow0 = (size_t)(myList[ar0] >> 1);
    arow1 = (size_t)(myList[ar1] >> 1);
  }
  const bf16_t* aptr0 = A + arow0 * K + skcol;
  const bf16_t* aptr1 = A + arow1 * K + skcol;
  const bf16_t* bptr0 = B + (size_t)(nblk * 128 + srow0) * K + skcol;
  const bf16_t* bptr1 = B + (size_t)(nblk * 128 + srow1) * K + skcol;

  const int ldsOfsA0 = (wid * 32) * 32;        // wave-uniform LDS offsets
  const int ldsOfsA1 = (wid * 32 + 16) * 32;

  f32x4 acc[4][4] = {};

  const int nkt = K >> 5;

  auto stage = [&](int buf, int kt) {
    const size_t ko = (size_t)kt * 32;
    gload_lds16(aptr0 + ko, &As[buf][ldsOfsA0]);
    gload_lds16(aptr1 + ko, &As[buf][ldsOfsA1]);
    gload_lds16(bptr0 + ko, &Bs[buf][ldsOfsA0]);
    gload_lds16(bptr1 + ko, &Bs[buf][ldsOfsA1]);
  };

  // prologue: prefetch tiles 0 and 1
  stage(0, 0);
  if (nkt > 1) stage(1, 1);

  // fragment read: row = (w*64 + m*16 + fr); (row>>1)&3 = (fr>>1)&3 for all m.
  const int fr = lane & 15;
  const int s0 = (((lane >> 4) ^ ((fr >> 1) & 3)) << 3);  // swizzled 8-elem slot

  int cur = 0;
  for (int kt = 0; kt < nkt; ++kt) {
    // issue tile kt+2 into the buffer whose last reads finished at iter kt-1
    int nxt = cur + 2;
    if (nxt >= 3) nxt -= 3;
    if (kt + 2 < nkt) {
      stage(nxt, kt + 2);
      asm volatile("s_waitcnt vmcnt(8)" ::: "memory");  // tile kt's 4 loads landed
    } else if (kt + 1 < nkt) {
      asm volatile("s_waitcnt vmcnt(4)" ::: "memory");
    } else {
      asm volatile("s_waitcnt vmcnt(0)" ::: "memory");
    }
    __builtin_amdgcn_s_barrier();  // all waves' tile-kt LDS writes visible

    bf16x8 af[4], bfr[4];
#pragma unroll
    for (int m = 0; m < 4; ++m)
      af[m] = *(const bf16x8*)&As[cur][(wr * 64 + m * 16 + fr) * 32 + s0];
#pragma unroll
    for (int n = 0; n < 4; ++n)
      bfr[n] = *(const bf16x8*)&Bs[cur][(wc * 64 + n * 16 + fr) * 32 + s0];
#pragma unroll
    for (int m = 0; m < 4; ++m)
#pragma unroll
      for (int n = 0; n < 4; ++n)
        acc[m][n] = __builtin_amdgcn_mfma_f32_16x16x32_bf16(af[m], bfr[n], acc[m][n], 0, 0, 0);

    __builtin_amdgcn_s_barrier();  // all reads of buf[cur] done before it is restaged
    cur += 1;
    if (cur >= 3) cur -= 3;
  }

  // epilogue: C row = (lane>>4)*4 + j (+16m), col = lane&15 (+16n)  [m89-verified]
  const int colBase = nblk * 128 + wc * 64 + (lane & 15);
  const int rowBase = mblk * 128 + wr * 64 + ((lane >> 4) << 2);
#pragma unroll
  for (int n = 0; n < 4; ++n) {
    const int c = colBase + n * 16;
    const float bv = bias[c];
#pragma unroll
    for (int m = 0; m < 4; ++m) {
#pragma unroll
      for (int j = 0; j < 4; ++j) {
        const int r = rowBase + m * 16 + j;
        float v = acc[m][n][j] + bv;
        if constexpr (MODE == 0) {
          ((bf16_t*)Cbase)[(size_t)r * N + c] = (bf16_t)v;
        } else if constexpr (MODE == 1) {
          if (r < Mloc) {
            v = fmaxf(v, 0.0f);
            ((bf16_t*)Cbase)[(size_t)(rowOff + r) * N + c] = (bf16_t)v;
          }
        } else if constexpr (MODE == 2) {
          if (r < Mloc) {
            const int entry = myList[r];
            const float w = myW[r];
            ((float*)Cbase)[(size_t)entry * DH + c] = v * w;
          }
        } else {
          ((float*)Cbase)[(size_t)r * N + c] = v;
        }
      }
    }
  }
}

// ---------------- launch ----------------

extern "C" void kernel_launch(void* const* d_in, const int* in_sizes, int n_in,
                              void* d_out, int out_size, void* d_ws, size_t ws_size,
                              hipStream_t stream) {
  const float* x      = (const float*)d_in[0];
  const float* W_in   = (const float*)d_in[1];
  const float* b_in   = (const float*)d_in[2];
  const float* W_gate = (const float*)d_in[3];
  const float* b_gate = (const float*)d_in[4];
  const float* W1     = (const float*)d_in[5];
  const float* b1     = (const float*)d_in[6];
  const float* W2     = (const float*)d_in[7];
  const float* b2     = (const float*)d_in[8];
  const float* W_out  = (const float*)d_in[9];
  const float* b_out  = (const float*)d_in[10];

  char* ws = (char*)d_ws;
  size_t off = 0;
  auto alloc = [&](size_t bytes) -> void* {
    void* p = ws + off;
    off += (bytes + 255) & ~(size_t)255;
    return p;
  };

  bf16_t* WtIn  = (bf16_t*)alloc((size_t)DH * DIN * 2);          // [DH][DIN]
  bf16_t* Wt1   = (bf16_t*)alloc((size_t)NEXP * DMOE * DH * 2);  // [E][DMOE][DH]
  bf16_t* Wt2   = (bf16_t*)alloc((size_t)NEXP * DH * DMOE * 2);  // [E][DH][DMOE]
  bf16_t* WtOut = (bf16_t*)alloc((size_t)DH * DH * 2);           // [DOUT][DH]
  bf16_t* xbf   = (bf16_t*)alloc((size_t)NTOK * DIN * 2);
  bf16_t* hbf   = (bf16_t*)alloc((size_t)NTOK * DH * 2);
  bf16_t* mid   = (bf16_t*)alloc((size_t)2 * NTOK * DMOE * 2);   // [2N][DMOE]
  float*  eout  = (float*)alloc((size_t)2 * NTOK * DH * 4);      // [2N][DH] (t*2+slot)
  bf16_t* moebf = (bf16_t*)alloc((size_t)NTOK * DH * 2);
  double* G     = (double*)alloc((size_t)DIN * 8 * 8);
  double* cvec  = (double*)alloc(8 * 8);
  int*    cnt   = (int*)alloc(NEXP * 4);
  int*    offs  = (int*)alloc((NEXP + 1) * 4);
  int*    list  = (int*)alloc((size_t)NEXP * NTOK * 4);
  float*  wlist = (float*)alloc((size_t)NEXP * NTOK * 4);

  k_zero8<<<1, 64, 0, stream>>>(cnt);

  k_transpose_cvt<<<dim3(DH / 64, DIN / 64, 1), 256, 0, stream>>>(W_in, WtIn, DIN, DH);
  k_transpose_cvt<<<dim3(DMOE / 64, DH / 64, NEXP), 256, 0, stream>>>(W1, Wt1, DH, DMOE);
  k_transpose_cvt<<<dim3(DH / 64, DMOE / 64, NEXP), 256, 0, stream>>>(W2, Wt2, DMOE, DH);
  k_transpose_cvt<<<dim3(DH / 64, DH / 64, 1), 256, 0, stream>>>(W_out, WtOut, DH, DH);
  k_cvt_bf16<<<(NTOK * DIN / 4 + 255) / 256, 256, 0, stream>>>(x, xbf, NTOK * DIN / 4);

  k_gate_prep<<<64, 256, 0, stream>>>(W_in, W_gate, b_in, b_gate, G, cvec);
  k_gating<<<NTOK / 4, 256, 0, stream>>>(x, G, cvec, cnt, list, wlist);
  k_scan<<<1, 64, 0, stream>>>(cnt, offs);

  // h = x @ W_in + b_in  (bf16 out)
  k_gemm<0><<<dim3(DH / 128, NTOK / 128, 1), 256, 0, stream>>>(
      xbf, WtIn, b_in, hbf, NTOK, DH, DIN, nullptr, nullptr, nullptr, nullptr);
  // mid = relu(h_gathered @ W1[e] + b1[e])
  k_gemm<1><<<dim3(DMOE / 128, NTOK / 128, NEXP), 256, 0, stream>>>(
      hbf, Wt1, b1, mid, NTOK, DMOE, DH, cnt, offs, list, wlist);
  // eout[t][slot] = (mid @ W2[e] + b2[e]) * route_w
  k_gemm<2><<<dim3(DH / 128, NTOK / 128, NEXP), 256, 0, stream>>>(
      mid, Wt2, b2, eout, NTOK, DH, DMOE, cnt, offs, list, wlist);
  k_combine<<<NTOK * DH / 4 / 256, 256, 0, stream>>>(eout, moebf);
  // out = moe @ W_out + b_out (fp32 out)
  k_gemm<3><<<dim3(DH / 128, NTOK / 128, 1), 256, 0, stream>>>(
      moebf, WtOut, b_out, (float*)d_out, NTOK, DH, DH, nullptr, nullptr, nullptr, nullptr);
}